// Round 4
// baseline (193.881 us; speedup 1.0000x reference)
//
#include <hip/hip_runtime.h>
#include <math.h>

typedef float vf4 __attribute__((ext_vector_type(4)));

// Bitonic network layer tables: l = blk*(blk+1)/2 + lay, m = 2^(blk-lay)
static constexpr int LLB[36] = {
  0,
  1,0,
  2,1,0,
  3,2,1,0,
  4,3,2,1,0,
  5,4,3,2,1,0,
  6,5,4,3,2,1,0,
  7,6,5,4,3,2,1,0
};
static constexpr int LBLK[36] = {
  0,
  1,1,
  2,2,2,
  3,3,3,3,
  4,4,4,4,4,
  5,5,5,5,5,5,
  6,6,6,6,6,6,6,
  7,7,7,7,7,7,7,7
};

// ---------------------------------------------------------------------------
// Kernel A: fused u-generation + blocks 0..5 (layers 0..20).
// U2 (layers 21..35) is written in the PERMUTED layout kernel B consumes:
//   in-thread layers (m>=4):  pos = (k>>4)*16 + (k&3)*4 + ((k>>2)&3)
//     -> float4 at [kg*4 + t4] = u[k] for k=16kg+4c+t4 (bank-disjoint
//        per-t4 quads -> conflict-free broadcast ds_read_b128)
//   quad-DPP layers (m<=2):   pos = (k>>3)*8 + (k&1)*4 + ((k>>1)&3)
//     -> float4 at [ag*2 + sel], element a&3
// ---------------------------------------------------------------------------
__global__ __launch_bounds__(256) void k_gen1(const float* __restrict__ vec,
                                              float* __restrict__ U2,
                                              float4* __restrict__ staged2) {
  const int b = blockIdx.x;
  const int tid = threadIdx.x;
  __shared__ __align__(16) float ub[36 * 128];   // 18 KB
  __shared__ float vv[256];
  vv[tid] = vec[b * 256 + tid];
  __syncthreads();

  const int k = tid & 127;
  if (tid < 128) {
    #pragma unroll
    for (int l = 0; l < 18; ++l) {
      const int lb = LLB[l], blk = LBLK[l];
      const int m = 1 << lb;
      const int p = ((k >> lb) << (lb + 1)) | (k & (m - 1));
      const int q = p + m;
      const int d = (p >> (blk + 1)) & 1;
      const float alpha =
          atanf(10.0f * (vv[q] - vv[p])) * 0.3183098861837907f + 0.5f;
      ub[l * 128 + k] = d ? (1.0f - alpha) : alpha;
    }
  } else {
    #pragma unroll
    for (int l = 18; l < 36; ++l) {
      const int lb = LLB[l], blk = LBLK[l];
      const int m = 1 << lb;
      const int p = ((k >> lb) << (lb + 1)) | (k & (m - 1));
      const int q = p + m;
      const int d = (p >> (blk + 1)) & 1;
      const float alpha =
          atanf(10.0f * (vv[q] - vv[p])) * 0.3183098861837907f + 0.5f;
      const float u = d ? (1.0f - alpha) : alpha;
      if (l < 21) ub[l * 128 + k] = u;
      if (l >= 21) {
        int pos;
        if (lb >= 2) pos = (k >> 4) * 16 + (k & 3) * 4 + ((k >> 2) & 3);
        else         pos = (k >> 3) * 8  + (k & 1) * 4 + ((k >> 1) & 3);
        U2[b * 1920 + (l - 21) * 128 + pos] = u;
      }
    }
  }
  __syncthreads();

  const int g  = tid >> 6;          // 64-col group (wave-uniform: wave == g)
  const int il = tid & 63;
  float r[64];
  #pragma unroll
  for (int j = 0; j < 64; ++j) r[j] = (j == il) ? 1.0f : 0.0f;

  #pragma unroll
  for (int l = 0; l < 21; ++l) {
    const int lb = LLB[l];
    const int m = 1 << lb;
    const float4* ulv = (const float4*)(ub + l * 128 + 32 * g);
    #pragma unroll
    for (int t = 0; t < 8; ++t) {
      const float4 u4 = ulv[t];     // ds_read_b128 broadcast (uniform addr)
      #pragma unroll
      for (int c = 0; c < 4; ++c) {
        const int kl = 4 * t + c;
        const int p = ((kl >> lb) << (lb + 1)) | (kl & (m - 1));
        const int q = p + m;
        const float u = (c == 0) ? u4.x : (c == 1) ? u4.y : (c == 2) ? u4.z : u4.w;
        const float t_  = r[p] - r[q];
        const float np = fmaf(u, t_, r[q]);
        const float nq = fmaf(-u, t_, r[p]);
        r[p] = np;
        r[q] = nq;
      }
    }
  }

  // coalesced store: per t, lanes il write 64 contiguous float4 (1KB)
  float4* sp = staged2 + ((size_t)(b * 4 + g) * 16) * 64 + il;
  #pragma unroll
  for (int t = 0; t < 16; ++t)
    sp[t * 64] = make_float4(r[4*t], r[4*t+1], r[4*t+2], r[4*t+3]);
}

// ---------------------------------------------------------------------------
// Kernel B: blocks 6..7 (layers 21..35), mod-4 column ownership.
// Block = (b, rowgroup g of 64 rows).  Thread = (wave w, r16, t4):
//   row = g*64 + w*16 + r16;  owns cols 4k+t4, k=0..63 (y[64]).
// All layers with m>=4 are thread-local butterflies (no LDS, no barriers).
// m=2 / m=1 layers exchange within a lane-quad via v_mov_dpp quad_perm (free).
// u comes from LDS (permuted U2 copy, conflict-free b128 broadcasts).
// Only LDS/barrier use: final output transpose (two 32KB passes).
// ---------------------------------------------------------------------------

// thread-local butterfly on pair kk of a layer with lb' = LBP (y-index space)
#define BFP(KK, LBP, UU) { \
  const int mp_ = 1 << (LBP); \
  const int p_ = (((KK) >> (LBP)) << ((LBP) + 1)) | ((KK) & (mp_ - 1)); \
  const float t_ = y[p_] - y[p_ + mp_]; \
  const float np_ = fmaf((UU), t_, y[p_ + mp_]); \
  const float nq_ = fmaf(-(UU), t_, y[p_]); \
  y[p_] = np_; y[p_ + mp_] = nq_; }

// in-thread layer LI (= l-21), pairs kk in [K0, K0+NP), lb' = LBP
#define INL(LI, LBP, K0, NP) { \
  const float4* uL4 = (const float4*)(up + (LI) * 128) + t4; \
  _Pragma("unroll") \
  for (int kg = (K0) >> 2; kg < ((K0) + (NP)) >> 2; ++kg) { \
    const float4 u4 = uL4[kg * 4]; \
    BFP(4*kg+0, LBP, u4.x) BFP(4*kg+1, LBP, u4.y) \
    BFP(4*kg+2, LBP, u4.z) BFP(4*kg+3, LBP, u4.w) } }

// quad-DPP butterfly on y[AA]; XM = quad_perm ctrl (0x4E: ^2, 0xB1: ^1)
#define DPPBF(AA, XM, UU) { \
  const float pv_ = __int_as_float(__builtin_amdgcn_mov_dpp( \
      __float_as_int(y[AA]), (XM), 0xF, 0xF, false)); \
  y[AA] = fmaf((UU), y[AA] - pv_, pv_); }

// DPP layer LI, elements a in [A0, A0+NA); SEL already folded into uD4 base
#define DPPL(LI, XM, SEL, A0, NA) { \
  const float4* uD4 = (const float4*)(up + (LI) * 128) + (SEL); \
  _Pragma("unroll") \
  for (int ag = (A0) >> 2; ag < ((A0) + (NA)) >> 2; ++ag) { \
    const float4 u4 = uD4[ag * 2]; \
    DPPBF(4*ag+0, XM, u4.x) DPPBF(4*ag+1, XM, u4.y) \
    DPPBF(4*ag+2, XM, u4.z) DPPBF(4*ag+3, XM, u4.w) } }

#define LOADY(BASE) { \
  _Pragma("unroll") \
  for (int j = 0; j < 16; ++j) y[(BASE) + j] = sp[j * 256]; }

// block-6 ladder restricted to the active 128-region (y-indices [RB, RB+32))
#define BLK6(RB) { \
  INL(0, 4, (RB)/2, 16)  /* l21 m=64  */ \
  INL(1, 3, (RB)/2, 16)  /* l22 m=32  */ \
  INL(2, 2, (RB)/2, 16)  /* l23 m=16  */ \
  INL(3, 1, (RB)/2, 16)  /* l24 m=8   */ \
  INL(4, 0, (RB)/2, 16)  /* l25 m=4   */ \
  DPPL(5, 0x4E, (t4 & 1),  (RB), 32)  /* l26 m=2 */ \
  DPPL(6, 0xB1, (t4 >> 1), (RB), 32)  /* l27 m=1 */ }

__global__ __launch_bounds__(256, 4) void k_phaseC(const float* __restrict__ U2,
                                                   const float* __restrict__ stagedF,
                                                   float* __restrict__ out) {
  const int bg = blockIdx.x;
  const int b = bg >> 2;
  const int g = bg & 3;
  const int tid = threadIdx.x;
  const int w   = tid >> 6;
  const int lane = tid & 63;
  const int t4  = lane & 3;
  const int r16 = lane >> 2;

  __shared__ __align__(16) float up[1920];   // 7.5 KB permuted u, l21..35
  __shared__ float4 ex[2048];                // 32 KB output transpose buffer

  float y[64];
  #pragma unroll
  for (int j = 0; j < 64; ++j) y[j] = 0.0f;

  // initial values: y[16g + j] = X[row][64g + 4j + t4]; per j the block reads
  // 1KB contiguous (float index = block_base + j*256 + tid)
  const float* sp = stagedF + (size_t)bg * 4096 + tid;
  // u copy (coalesced; layout already permuted by k_gen1)
  const float* u2b = U2 + b * 1920;
  #pragma unroll
  for (int it = 0; it < 8; ++it) {
    const int idx = it * 256 + tid;
    if (idx < 1920) up[idx] = u2b[idx];
  }

  if (g == 0)      { LOADY(0)  }
  else if (g == 1) { LOADY(16) }
  else if (g == 2) { LOADY(32) }
  else             { LOADY(48) }

  __syncthreads();   // up[] ready

  // ---- block 6 (l21..27): only the active 128-region has nonzeros
  if ((g >> 1) == 0) { BLK6(0) } else { BLK6(32) }

  // ---- block 7 (l28..35): full width, all thread-local / quad-DPP
  INL(7,  5, 0, 32)   // l28 m=128
  INL(8,  4, 0, 32)   // l29 m=64
  INL(9,  3, 0, 32)   // l30 m=32
  INL(10, 2, 0, 32)   // l31 m=16
  INL(11, 1, 0, 32)   // l32 m=8
  INL(12, 0, 0, 32)   // l33 m=4
  DPPL(13, 0x4E, (t4 & 1),  0, 64)   // l34 m=2
  DPPL(14, 0xB1, (t4 >> 1), 0, 64)   // l35 m=1

  // ---- output: XOR-swizzled LDS transpose, two 32-row (32KB) passes.
  // write: word = rp*256 + ((4a + t4) ^ (4*(r16&7)))  -> 2-way max (free)
  // read:  float4 slot q^(rp&7) of row rp             -> conflict-free
  float* exf = (float*)ex;
  float4* out4 = (float4*)out + ((size_t)(b * 256 + g * 64)) * 64;

  if (w < 2) {
    const int rp = (w << 4) | r16;
    const int sw = 4 * (r16 & 7);
    #pragma unroll
    for (int a = 0; a < 64; ++a)
      exf[rp * 256 + ((4 * a + t4) ^ sw)] = y[a];
  }
  __syncthreads();
  #pragma unroll
  for (int it = 0; it < 8; ++it) {
    const int fq = it * 256 + tid;
    const int rp = fq >> 6, q = fq & 63;
    const float4 v4 = ex[rp * 64 + (q ^ (rp & 7))];
    __builtin_nontemporal_store(*(const vf4*)&v4, (vf4*)&out4[rp * 64 + q]);
  }
  __syncthreads();
  if (w >= 2) {
    const int rp = ((w - 2) << 4) | r16;
    const int sw = 4 * (r16 & 7);
    #pragma unroll
    for (int a = 0; a < 64; ++a)
      exf[rp * 256 + ((4 * a + t4) ^ sw)] = y[a];
  }
  __syncthreads();
  #pragma unroll
  for (int it = 0; it < 8; ++it) {
    const int fq = it * 256 + tid;
    const int rp = fq >> 6, q = fq & 63;
    const float4 v4 = ex[rp * 64 + (q ^ (rp & 7))];
    __builtin_nontemporal_store(*(const vf4*)&v4,
                                (vf4*)&out4[2048 + rp * 64 + q]);
  }
}

// ---------------------------------------------------------------------------
extern "C" void kernel_launch(void* const* d_in, const int* in_sizes, int n_in,
                              void* d_out, int out_size, void* d_ws, size_t ws_size,
                              hipStream_t stream) {
  const float* vec = (const float*)d_in[0];   // vectors (512,256) f32
  float* out = (float*)d_out;                 // (512,256,256) f32
  float* U2 = (float*)d_ws;                   // 512*1920 f32 = 3.93 MB (l 21..35, permuted)
  float* staged2 = U2 + (size_t)512 * 1920;   // 512*4096 f32 = 33.5 MB

  hipLaunchKernelGGL(k_gen1,   dim3(512),  dim3(256), 0, stream, vec, U2,
                     (float4*)staged2);
  hipLaunchKernelGGL(k_phaseC, dim3(2048), dim3(256), 0, stream, U2, staged2, out);
}